// Round 1
// 1337.924 us; speedup vs baseline: 1.0162x; 1.0162x over previous
//
#include <hip/hip_runtime.h>

typedef _Float16 half8_t __attribute__((ext_vector_type(8)));
typedef float    f32x4   __attribute__((ext_vector_type(4)));

#define T_STEPS 1024
#define BATCH   128
#define HID     128
#define GATES   512
#define STACK   1024

__device__ __forceinline__ float sigf(float x)     { return 1.0f / (1.0f + __expf(-x)); }
__device__ __forceinline__ float tanhfast(float x) { return 1.0f - 2.0f / (1.0f + __expf(2.0f * x)); }

// grid = 256: blocks [0,128) = layer 0 of row r, [128,256) = layer 1 of row r.
// Matvec on the MFMA pipe (16x16x32 f16, N=1 broadcast-B). Weights persist as
// A-fragments (AGPR-resident).
//
// Round N change: gate-interleaved weight-row permutation. Tile i, frag row m
// maps to weight row 128*(m&3) + 16*wv + 4*i + (m>>2), so accumulator a_i[reg]
// at lane (ml,kg) = gate 'reg' of unit 16wv+4i+kg. Each lane owns ONE unit's
// four gates after 12 v_cndmask (tile select by ml>>2) -> epilogue is
// lane-local: the gl LDS round trip and barrier A are deleted.
// The single remaining per-step barrier is a raw lgkmcnt(0)+s_barrier (no
// vmcnt drain): ring stores / out stores / spec loads / input prefetches stay
// in flight across steps instead of being drained twice per step by
// __syncthreads' implicit s_waitcnt vmcnt(0).
// Cross-block: self-validating tagged u32 ring words, relaxed agent atomics.
__launch_bounds__(512, 2)
__global__ void stack_lstm_pipe(const float* __restrict__ inputs,
                                const int*   __restrict__ ops,
                                const float* __restrict__ w_ih,
                                const float* __restrict__ w_hh,
                                const float* __restrict__ b_ih,
                                const float* __restrict__ b_hh,
                                float* __restrict__ out,
                                unsigned int* __restrict__ ring,  // [D][BATCH][HID]
                                int* __restrict__ cons,           // [BATCH] watermark
                                int D)                            // ring depth, pow2
{
    const int bx    = blockIdx.x;
    const int layer = bx >> 7;      // 0 or 1
    const int r     = bx & 127;     // batch row
    const int tid   = threadIdx.x;  // 0..511
    const int wv    = tid >> 6;     // wave 0..7
    const int ln    = tid & 63;
    const int ml    = ln & 15;      // m within 16x16 tile
    const int kg    = ln >> 4;      // k-group 0..3
    const int isel  = ml >> 2;      // which tile this lane's epilogue consumes
    const int unit  = 16 * wv + 4 * isel + kg;  // unit this lane owns (4x redundant over ml&3)
    const bool uw   = ((ml & 3) == 0);          // unique writer lane for this unit
    const int mask  = D - 1;

    __shared__ __align__(16) _Float16 vin[2][256];  // [x(128) | h_top(128)]
    __shared__ int ops_s[T_STEPS];

    // ---- weights as MFMA A-fragments, gate-interleaved rows:
    // tile i, frag row m -> weight row 128*(m&3) + 16*wv + 4*i + (m>>2).
    // Virtual K-axis: k<128 -> w_ih cols, k>=128 -> w_hh cols.
    half8_t wfrag[32];  // [i*8 + kc]
#pragma unroll
    for (int i = 0; i < 4; ++i) {
        const int R = 128 * (ml & 3) + 16 * wv + 4 * i + (ml >> 2);
        const float* rowi = w_ih + (size_t)(layer * GATES + R) * HID;
        const float* rowh = w_hh + (size_t)(layer * GATES + R) * HID;
#pragma unroll
        for (int kc = 0; kc < 8; ++kc) {
            const int k0 = 32 * kc + 8 * kg;
            const float* src = (k0 < 128) ? (rowi + k0) : (rowh + (k0 - 128));
            half8_t h;
#pragma unroll
            for (int j = 0; j < 8; j += 2) {
                float2 f = *reinterpret_cast<const float2*>(src + j);
                h[j]     = (_Float16)f.x;
                h[j + 1] = (_Float16)f.y;
            }
            wfrag[i * 8 + kc] = h;
        }
    }
    // biases for the 4 gates of this lane's unit
    float Bb[4];
#pragma unroll
    for (int g = 0; g < 4; ++g)
        Bb[g] = b_ih[layer * GATES + 128 * g + unit] + b_hh[layer * GATES + 128 * g + unit];

    ops_s[tid]       = ops[(size_t)tid * BATCH + r];
    ops_s[tid + 512] = ops[(size_t)(tid + 512) * BATCH + r];

    const bool stager = (tid >= 128 && tid < 256);
    const int  su     = tid - 128;

    float c_cur = 0.f, h_top = 0.f;
    int   pos = 0, cons_seen = 0;
    float xs = 0.f;  // L0 stagers: x(t+1) pipeline register

    // ---- initial staging: vin[0] = [x(0) or h0(0) | zeros]
    if (stager) {
        if (layer == 0) {
            vin[0][su] = (_Float16)inputs[(size_t)r * HID + su];
            xs = inputs[(size_t)BATCH * HID + (size_t)r * HID + su];  // x(1)
        } else {
            unsigned int v;
            do {
                v = __hip_atomic_load(ring + (size_t)r * HID + su,
                                      __ATOMIC_RELAXED, __HIP_MEMORY_SCOPE_AGENT);
                if ((v & 0xFFFFu) == 1u) break;
                __builtin_amdgcn_s_sleep(1);
            } while (true);
            vin[0][su] = __builtin_bit_cast(_Float16, (unsigned short)(v >> 16));
        }
    }
    if (tid < HID) vin[0][HID + tid] = (_Float16)0.f;
    __syncthreads();

    for (int t = 0; t < T_STEPS; ++t) {
        const int buf = t & 1, nb = buf ^ 1;

        // speculative ring load for step t+1 (L1 stagers) — hides the round trip
        unsigned int spec = 0;
        if (layer == 1 && stager && t + 1 < T_STEPS)
            spec = __hip_atomic_load(ring + (size_t)((t + 1) & mask) * BATCH * HID
                                          + (size_t)r * HID + su,
                                     __ATOMIC_RELAXED, __HIP_MEMORY_SCOPE_AGENT);

        // ---- S1: matvec on the MFMA pipe. B-frag address is lane&15-free:
        // all lanes broadcast-load the same vector chunk, so all 16 C columns
        // hold the matvec result (no masking needed).
        f32x4 a0 = {0.f, 0.f, 0.f, 0.f}, a1 = a0, a2 = a0, a3 = a0;
#pragma unroll
        for (int kc = 0; kc < 8; ++kc) {
            const half8_t bfrag =
                *reinterpret_cast<const half8_t*>(&vin[buf][32 * kc + 8 * kg]);
            a0 = __builtin_amdgcn_mfma_f32_16x16x32_f16(wfrag[kc],      bfrag, a0, 0, 0, 0);
            a1 = __builtin_amdgcn_mfma_f32_16x16x32_f16(wfrag[8 + kc],  bfrag, a1, 0, 0, 0);
            a2 = __builtin_amdgcn_mfma_f32_16x16x32_f16(wfrag[16 + kc], bfrag, a2, 0, 0, 0);
            a3 = __builtin_amdgcn_mfma_f32_16x16x32_f16(wfrag[24 + kc], bfrag, a3, 0, 0, 0);
        }

        // ---- S2: lane-local epilogue. Select this lane's tile (isel) —
        // gv[reg] = gate 'reg' (i,f,g,o) of 'unit'. 12 v_cndmask, no LDS.
        f32x4 s01 = (isel & 1) ? a1 : a0;
        f32x4 s23 = (isel & 1) ? a3 : a2;
        f32x4 gv  = (isel & 2) ? s23 : s01;

        const int   op    = ops_s[t];
        const float c_new = sigf(gv[1] + Bb[1]) * c_cur
                          + sigf(gv[0] + Bb[0]) * tanhfast(gv[2] + Bb[2]);
        const float h_new = sigf(gv[3] + Bb[3]) * tanhfast(c_new);
        const float h_sel = op ? h_new : h_top;

        if (uw) {
            vin[nb][HID + unit] = (_Float16)h_sel;
            if (layer == 0) {
                const unsigned short hs = __builtin_bit_cast(unsigned short, (_Float16)h_new);
                if (D < T_STEPS && t >= D) {  // ring backpressure (rare)
                    const int need = t - D;
                    while (cons_seen < need) {
                        cons_seen = __hip_atomic_load(cons + r, __ATOMIC_RELAXED,
                                                      __HIP_MEMORY_SCOPE_AGENT);
                        if (cons_seen >= need) break;
                        __builtin_amdgcn_s_sleep(1);
                    }
                }
                __hip_atomic_store(ring + (size_t)(t & mask) * BATCH * HID
                                        + (size_t)r * HID + unit,
                                   ((unsigned int)hs << 16) | (unsigned int)((t + 1) & 0xFFFF),
                                   __ATOMIC_RELAXED, __HIP_MEMORY_SCOPE_AGENT);
            } else {
                out[(size_t)(pos + 1) * BATCH * HID + (size_t)r * HID + unit] = h_new;
            }
        }
        h_top = h_sel;
        c_cur = op ? c_new : c_cur;
        pos += op;

        // ---- stage next step's x-part
        if (stager && t + 1 < T_STEPS) {
            if (layer == 0) {
                vin[nb][su] = (_Float16)xs;
                if (t + 2 < T_STEPS)
                    xs = inputs[(size_t)(t + 2) * BATCH * HID + (size_t)r * HID + su];
            } else {
                unsigned int v = spec;
                const unsigned int expect = (unsigned int)((t + 2) & 0xFFFF);
                while ((v & 0xFFFFu) != expect) {
                    __builtin_amdgcn_s_sleep(1);
                    v = __hip_atomic_load(ring + (size_t)((t + 1) & mask) * BATCH * HID
                                               + (size_t)r * HID + su,
                                          __ATOMIC_RELAXED, __HIP_MEMORY_SCOPE_AGENT);
                }
                vin[nb][su] = __builtin_bit_cast(_Float16, (unsigned short)(v >> 16));
            }
        }
        // consumer progress watermark (backpressure input; relaxed, lag-safe)
        if (layer == 1 && tid == 256 && (t & 15) == 0)
            __hip_atomic_store(cons + r, t - 1, __ATOMIC_RELAXED, __HIP_MEMORY_SCOPE_AGENT);

        // ---- raw barrier: LDS-drain only. Global loads issued above are
        // waited at their use via per-register vmcnt tracking; global stores
        // are fire-and-forget (tagged-word protocol self-validates).
        asm volatile("s_waitcnt lgkmcnt(0)\n\ts_barrier" ::: "memory");
    }

    // final pos (float32 — exact for ints <= 1024)
    if (layer == 1 && tid == 0)
        out[(size_t)(STACK + 1) * BATCH * HID + r] = (float)pos;
}

extern "C" void kernel_launch(void* const* d_in, const int* in_sizes, int n_in,
                              void* d_out, int out_size, void* d_ws, size_t ws_size,
                              hipStream_t stream)
{
    (void)in_sizes; (void)n_in;
    const float* inputs = (const float*)d_in[0];
    const int*   ops    = (const int*)d_in[1];
    const float* w_ih   = (const float*)d_in[2];
    const float* w_hh   = (const float*)d_in[3];
    const float* b_ih   = (const float*)d_in[4];
    const float* b_hh   = (const float*)d_in[5];
    float* out = (float*)d_out;

    // ws layout: [0,4096) cons watermark, then tagged u32 ring [D][128][128]
    int* cons = (int*)d_ws;
    unsigned int* ring = (unsigned int*)((char*)d_ws + 4096);

    size_t slot_bytes = (size_t)BATCH * HID * sizeof(unsigned int);
    size_t avail = (ws_size > 4096) ? (ws_size - 4096) / slot_bytes : 1;
    int D = 1;
    while ((size_t)(D * 2) <= avail && D < T_STEPS) D *= 2;

    hipMemsetAsync(d_ws, 0, 4096, stream);  // zero watermarks
    // ring starts 0xAA-poisoned: tag 0xAAAA never matches (expect <= 1025)
    // slots never reached by pos+1 must be zero
    hipMemsetAsync(d_out, 0, (size_t)out_size * sizeof(float), stream);

    stack_lstm_pipe<<<dim3(256), dim3(512), 0, stream>>>(
        inputs, ops, w_ih, w_hh, b_ih, b_hh, out, ring, cons, D);
}